// Round 9
// baseline (161.285 us; speedup 1.0000x reference)
//
#include <hip/hip_runtime.h>

typedef __attribute__((ext_vector_type(8))) short bf16x8;
typedef __attribute__((ext_vector_type(4))) float f32x4;
typedef __attribute__((ext_vector_type(4))) unsigned short u16x4;
typedef unsigned short u16;
typedef unsigned int u32;

#define MFMA16(a,b,c) __builtin_amdgcn_mfma_f32_16x16x32_bf16(a,b,c,0,0,0)

// ---------- f32 -> (bf16 hi, bf16 lo) split ----------
// hi = truncate-to-bf16; lo = bf16(x - hi). 3-product MFMA ~ fp32-class accuracy.
__device__ __forceinline__ void split_f32(float x, u16 &hi, u16 &lo){
  unsigned u = __float_as_uint(x);
  unsigned hif = u & 0xFFFF0000u;
  float rest = x - __uint_as_float(hif);
  hi = (u16)(u >> 16);
  lo = (u16)(__float_as_uint(rest) >> 16);
}

__device__ __forceinline__ void gload_lds16(const void* g, void* l){
  __builtin_amdgcn_global_load_lds((const __attribute__((address_space(1))) u32*)g,
                                   (__attribute__((address_space(3))) u32*)l, 16, 0, 0);
}

// ---------- prep: c vectors, folded Wc = hw@wv, bc = hw@bv+hb, W2 split+interleave ----------
__global__ __launch_bounds__(128) void prep_kernel(
    const float* __restrict__ v1, const float* __restrict__ v2,
    const float* __restrict__ mt_w1, const float* __restrict__ mt_b1,
    const float* __restrict__ mt_w2, const float* __restrict__ mt_b2,
    const float* __restrict__ mt_wv, const float* __restrict__ mt_bv,
    const float* __restrict__ mts_w1, const float* __restrict__ mts_b1,
    const float* __restrict__ mts_w2, const float* __restrict__ mts_b2,
    const float* __restrict__ mts_wv, const float* __restrict__ mts_bv,
    const float* __restrict__ ht_w, const float* __restrict__ ht_b,
    const float* __restrict__ hts_w, const float* __restrict__ hts_b,
    u16* __restrict__ w2a, u16* __restrict__ w2b,
    u16* __restrict__ wc1, u16* __restrict__ wc2,
    float* __restrict__ c1, float* __restrict__ c2,
    float* __restrict__ bc1, float* __restrict__ bc2)
{
  const int blk = blockIdx.x;
  const int t = threadIdx.x;   // 128 threads
  if (blk < 128) {
    const bool second = blk >= 64;
    const int b = blk & 63;
    const float* x  = second ? v1 : v2;
    const float* w1 = second ? mts_w1 : mt_w1;
    const float* b1 = second ? mts_b1 : mt_b1;
    const float* b2 = second ? mts_b2 : mt_b2;
    float* c = second ? c2 : c1;
    __shared__ float xr[128];
    xr[t] = x[b*128 + t];
    __syncthreads();
    float s = 0.f;
    #pragma unroll 8
    for (int k=0;k<128;k++) s += w1[t*128 + k] * xr[k];
    c[b*128 + t] = s + b1[t] - b2[t];
  } else if (blk < 384) {
    const bool second = blk >= 256;
    const int e = blk - (second ? 256 : 128);
    const float* hw = second ? hts_w : ht_w;
    const float* wv = second ? mts_wv : mt_wv;
    const float* bv = second ? mts_bv : mt_bv;
    const float* hb = second ? hts_b : ht_b;
    u16* wc = second ? wc2 : wc1;
    float* bcp = second ? bc2 : bc1;
    float s = 0.f;
    #pragma unroll 8
    for (int k=0;k<128;k++) s += hw[e*128 + k] * wv[k*128 + t];
    u16 hi, lo; split_f32(s, hi, lo);
    int oi = e*256 + ((t>>3)<<4) + (t&7);
    wc[oi] = hi; wc[oi+8] = lo;
    __shared__ float red[128];
    red[t] = hw[e*128 + t] * bv[t];
    __syncthreads();
    for (int off=64; off>0; off>>=1){ if (t<off) red[t] += red[t+off]; __syncthreads(); }
    if (t==0) bcp[e] = red[0] + hb[e];
  } else {
    const int i = (blk-384)*128 + t;
    const int r = i >> 7, col = i & 127;
    const int oi = r*256 + ((col>>3)<<4) + (col&7);
    u16 hi, lo;
    split_f32(mt_w2[i], hi, lo);  w2a[oi] = hi; w2a[oi+8] = lo;
    split_f32(mts_w2[i], hi, lo); w2b[oi] = hi; w2b[oi+8] = lo;
  }
}

// ---------- main: 1024 blocks x 512 thr (1 block/CU), 4 tiles each ----------
// reg-resident weights; FUSED cross-tile phase: iteration i runs GEMM23(tile i-1)
// interleaved with GEMM1(tile i) in one k-loop (2 independent MFMA chains/wave).
// 2 barriers per tile; counted vmcnt keeps next gather in flight across barriers.
__global__ __launch_bounds__(512, 2) void main_kernel(
    const u16* __restrict__ mh, const u16* __restrict__ ml,
    const int* __restrict__ idx,
    const u16* __restrict__ w2a, const u16* __restrict__ w2b,
    const u16* __restrict__ wc1, const u16* __restrict__ wc2,
    const float* __restrict__ c1, const float* __restrict__ c2,
    const float* __restrict__ bc1, const float* __restrict__ bc2,
    float* __restrict__ wss)
{
  __shared__ u16 Mbuf[2][2][64*128];   // [buf][hi/lo] M double buffer (64KB)
  __shared__ u16 Pln[4][64*128];       // P1h,P1l,P2h,P2l contiguous (64KB)
  __shared__ float part[8][64][3];     // 6KB

  const int tid  = threadIdx.x;
  const int wid  = tid >> 6;        // 0..7 -> d' slice [wid*16, wid*16+16)
  const int lane = tid & 63;
  const int lg = lane >> 4, li = lane & 15;

  // ---- prologue: weights -> registers (row d'=wid*16+li, chunk k*4+lg, 8hi|8lo) ----
  const int wbase = (wid*16 + li)*256 + lg*16;
  bf16x8 W2aH[4], W2aL[4], W2bH[4], W2bL[4], VcaH[4], VcaL[4], VcbH[4], VcbL[4];
  #pragma unroll
  for (int k=0;k<4;k++){
    W2aH[k] = *(const bf16x8*)(w2a + wbase + k*64);
    W2aL[k] = *(const bf16x8*)(w2a + wbase + k*64 + 8);
    W2bH[k] = *(const bf16x8*)(w2b + wbase + k*64);
    W2bL[k] = *(const bf16x8*)(w2b + wbase + k*64 + 8);
    VcaH[k] = *(const bf16x8*)(wc1 + wbase + k*64);
    VcaL[k] = *(const bf16x8*)(wc1 + wbase + k*64 + 8);
    VcbH[k] = *(const bf16x8*)(wc2 + wbase + k*64);
    VcbL[k] = *(const bf16x8*)(wc2 + wbase + k*64 + 8);
  }

  const int bid = blockIdx.x;      // 1024 blocks; b constant per block
  const int b = bid >> 4;          // 0..63
  const int sbase = (bid & 15) * 256;   // 4 tiles of 64 s each

  // ---- idx prefetch for ALL 4 tiles -> register offsets ----
  const int q = lane >> 4, sl = lane & 15;
  u32 goff[4][2];
  #pragma unroll
  for (int I=0;I<4;I++){
    #pragma unroll
    for (int j=0;j<2;j++){
      const int grow = wid*8 + j*4 + q;
      const int ridx = idx[b*4096 + sbase + I*64 + grow];
      goff[I][j] = (u32)ridx*128 + (u32)((sl ^ (grow&15))*8);
    }
  }

  #define DO_GATHER(I, BUF) {                                        \
    _Pragma("unroll")                                                \
    for (int j=0;j<2;j++){                                           \
      gload_lds16(mh + goff[I][j], &Mbuf[BUF][0][(wid*8 + j*4)*128]); \
      gload_lds16(ml + goff[I][j], &Mbuf[BUF][1][(wid*8 + j*4)*128]); \
    }                                                                \
  }

  DO_GATHER(0, 0);

  #pragma unroll
  for (int i=0; i<5; ++i){
    if (i <= 2) DO_GATHER(i+1, (i+1)&1);   // in flight until B2(i)
    if (i == 0){
      asm volatile("s_waitcnt vmcnt(4)" ::: "memory");   // gather(0) landed
      __builtin_amdgcn_s_barrier();
      __builtin_amdgcn_sched_barrier(0);
    }

    f32x4 acc1[4], acc2[4], h1[4], h2[4];
    if (i <= 3){
      #pragma unroll
      for (int n=0;n<4;n++){ acc1[n]=(f32x4)(0.f); acc2[n]=(f32x4)(0.f); }
    }
    if (i >= 1){
      #pragma unroll
      for (int n=0;n<4;n++){ h1[n]=(f32x4)(0.f); h2[n]=(f32x4)(0.f); }
    }
    const u16* mch = &Mbuf[i&1][0][0];
    const u16* mcl = &Mbuf[i&1][1][0];

    // ---- FUSED phase: GEMM23(i-1) [P planes] + GEMM1(i) [M buf] ----
    #pragma unroll
    for (int k=0;k<4;k++){
      __builtin_amdgcn_s_setprio(1);
      #pragma unroll
      for (int n=0;n<4;n++){
        const int a = (n*16+li)*128 + (((k*4+lg) ^ li)<<3);
        if (i >= 1){
          bf16x8 p1h = *(const bf16x8*)(&Pln[0][a]);
          bf16x8 p1l = *(const bf16x8*)(&Pln[1][a]);
          bf16x8 p2h = *(const bf16x8*)(&Pln[2][a]);
          bf16x8 p2l = *(const bf16x8*)(&Pln[3][a]);
          h1[n] = MFMA16(VcaH[k], p1h, h1[n]);
          h2[n] = MFMA16(VcbH[k], p2h, h2[n]);
          h1[n] = MFMA16(VcaH[k], p1l, h1[n]);
          h2[n] = MFMA16(VcbH[k], p2l, h2[n]);
          h1[n] = MFMA16(VcaL[k], p1h, h1[n]);
          h2[n] = MFMA16(VcbL[k], p2h, h2[n]);
        }
        if (i <= 3){
          bf16x8 bh = *(const bf16x8*)(mch + a);
          bf16x8 bl = *(const bf16x8*)(mcl + a);
          acc1[n] = MFMA16(W2aH[k], bh, acc1[n]);
          acc2[n] = MFMA16(W2bH[k], bh, acc2[n]);
          acc1[n] = MFMA16(W2aH[k], bl, acc1[n]);
          acc2[n] = MFMA16(W2bH[k], bl, acc2[n]);
          acc1[n] = MFMA16(W2aL[k], bh, acc1[n]);
          acc2[n] = MFMA16(W2bL[k], bh, acc2[n]);
        }
      }
      __builtin_amdgcn_s_setprio(0);
    }

    // ---- part write for tile i-1 ----
    if (i >= 1){
      const float4 bb1 = *(const float4*)(bc1 + wid*16 + lg*4);
      const float4 bb2 = *(const float4*)(bc2 + wid*16 + lg*4);
      #pragma unroll
      for (int n=0;n<4;n++){
        float p11=0.f, p22=0.f, p12=0.f;
        #pragma unroll
        for (int r=0;r<4;r++){
          float e1 = (r==0)?bb1.x:(r==1)?bb1.y:(r==2)?bb1.z:bb1.w;
          float e2 = (r==0)?bb2.x:(r==1)?bb2.y:(r==2)?bb2.z:bb2.w;
          float v1h = h1[n][r] + e1;
          float v2h = h2[n][r] + e2;
          p11 += v1h*v1h; p22 += v2h*v2h; p12 += v1h*v2h;
        }
        p11 += __shfl_xor(p11, 16, 64); p11 += __shfl_xor(p11, 32, 64);
        p22 += __shfl_xor(p22, 16, 64); p22 += __shfl_xor(p22, 32, 64);
        p12 += __shfl_xor(p12, 16, 64); p12 += __shfl_xor(p12, 32, 64);
        if (lane < 16){
          part[wid][n*16+li][0] = p11;
          part[wid][n*16+li][1] = p22;
          part[wid][n*16+li][2] = p12;
        }
      }
    }

    // B1: fused-phase LDS reads done; part visible
    asm volatile("s_waitcnt lgkmcnt(0)" ::: "memory");
    __builtin_amdgcn_s_barrier();
    __builtin_amdgcn_sched_barrier(0);

    // ---- pre-write(i): relu(c - T) -> P planes (overwrites; fenced by B1) ----
    if (i <= 3){
      const float4 cv1 = *(const float4*)(c1 + b*128 + wid*16 + lg*4);
      const float4 cv2 = *(const float4*)(c2 + b*128 + wid*16 + lg*4);
      const int c = wid*2 + (lg>>1);
      const int sub = (lg&1)*4;
      #pragma unroll
      for (int n=0;n<4;n++){
        const int row = n*16 + li;
        const int a2 = row*128 + ((c ^ li)<<3) + sub;
        u16x4 h4, l4, g4, m4;
        #pragma unroll
        for (int r=0;r<4;r++){
          float c1r = (r==0)?cv1.x:(r==1)?cv1.y:(r==2)?cv1.z:cv1.w;
          float c2r = (r==0)?cv2.x:(r==1)?cv2.y:(r==2)?cv2.z:cv2.w;
          float p1 = fmaxf(c1r - acc1[n][r], 0.f);
          float p2 = fmaxf(c2r - acc2[n][r], 0.f);
          u16 hh, ll;
          split_f32(p1, hh, ll); h4[r]=hh; l4[r]=ll;
          split_f32(p2, hh, ll); g4[r]=hh; m4[r]=ll;
        }
        *(u16x4*)&Pln[0][a2] = h4; *(u16x4*)&Pln[1][a2] = l4;
        *(u16x4*)&Pln[2][a2] = g4; *(u16x4*)&Pln[3][a2] = m4;
      }
    }

    // ---- score(i-1) from part ----
    if (i >= 1 && tid < 64){
      float S11=0.f, S22=0.f, S12=0.f;
      #pragma unroll
      for (int w=0; w<8; w++){
        S11 += part[w][tid][0]; S22 += part[w][tid][1]; S12 += part[w][tid][2];
      }
      float dot = S12 / sqrtf(S11 * S22);
      wss[(size_t)b*4096 + sbase + (i-1)*64 + tid] = expf((dot - 1.0f) * (1.0f/0.07f));
    }

    // B2: pre planes visible; gather(i+1) landed (cover = full fused phase)
    if (i < 4){
      asm volatile("s_waitcnt vmcnt(0) lgkmcnt(0)" ::: "memory");
      __builtin_amdgcn_s_barrier();
      __builtin_amdgcn_sched_barrier(0);
    }
  }
  #undef DO_GATHER
}

// ---------- split (+ optional copy): bank -> hi/lo planes ----------
__global__ __launch_bounds__(256) void split_copy_kernel(const float4* __restrict__ src,
    float4* __restrict__ dst, u16x4* __restrict__ mhp, u16x4* __restrict__ mlp,
    int n4, int docopy)
{
  int i = blockIdx.x*256 + threadIdx.x;
  const int stride = gridDim.x*256;
  for (; i < n4; i += stride){
    float4 f = src[i];
    if (docopy) dst[i] = f;
    u16x4 h, l; u16 hh, ll;
    split_f32(f.x, hh, ll); h[0]=hh; l[0]=ll;
    split_f32(f.y, hh, ll); h[1]=hh; l[1]=ll;
    split_f32(f.z, hh, ll); h[2]=hh; l[2]=ll;
    split_f32(f.w, hh, ll); h[3]=hh; l[3]=ll;
    mhp[i] = h; mlp[i] = l;
  }
}

__global__ __launch_bounds__(256) void copy_kernel(const float4* __restrict__ src,
                                                   float4* __restrict__ dst, int n4)
{
  int i = blockIdx.x*256 + threadIdx.x;
  const int stride = gridDim.x*256;
  for (; i < n4; i += stride) dst[i] = src[i];
}

__global__ __launch_bounds__(128) void update_kernel(const float* __restrict__ mem,
    const float* __restrict__ v2, const int* __restrict__ y, float* __restrict__ outmem)
{
  const int b = blockIdx.x;
  const int t = threadIdx.x;
  const int row = y[b];
  for (int b2=b+1; b2<64; ++b2) if (y[b2] == row) return;   // later duplicate wins
  float ab = 0.5f*mem[(size_t)row*128 + t] + 0.5f*v2[b*128 + t];
  __shared__ float red[2];
  float s = ab*ab;
  #pragma unroll
  for (int off=1; off<64; off<<=1) s += __shfl_xor(s, off, 64);
  if ((t & 63) == 0) red[t>>6] = s;
  __syncthreads();
  float tot = red[0] + red[1];
  outmem[(size_t)row*128 + t] = ab / sqrtf(tot);
}

// scores wss[b][s] -> out[s][b]
__global__ __launch_bounds__(256) void transpose_kernel(const float* __restrict__ wss,
                                                        float* __restrict__ out)
{
  __shared__ float tile[64][65];
  const int t = blockIdx.x;
  const int c = threadIdx.x & 63;
  const int r4 = threadIdx.x >> 6;
  #pragma unroll
  for (int i=0;i<16;i++){
    int bb = i*4 + r4;
    tile[bb][c] = wss[(size_t)bb*4096 + t*64 + c];
  }
  __syncthreads();
  #pragma unroll
  for (int i=0;i<16;i++){
    int s = i*4 + r4;
    out[(size_t)(t*64+s)*64 + c] = tile[c][s];
  }
}

extern "C" void kernel_launch(void* const* d_in, const int* in_sizes, int n_in,
                              void* d_out, int out_size, void* d_ws, size_t ws_size,
                              hipStream_t stream) {
  (void)in_sizes; (void)n_in; (void)out_size;
  const float* v1      = (const float*)d_in[0];
  const float* v2      = (const float*)d_in[1];
  const float* mem     = (const float*)d_in[2];
  const float* mt_w1   = (const float*)d_in[3];
  const float* mt_b1   = (const float*)d_in[4];
  const float* mt_w2   = (const float*)d_in[5];
  const float* mt_b2   = (const float*)d_in[6];
  const float* mt_wv   = (const float*)d_in[7];
  const float* mt_bv   = (const float*)d_in[8];
  const float* mts_w1  = (const float*)d_in[9];
  const float* mts_b1  = (const float*)d_in[10];
  const float* mts_w2  = (const float*)d_in[11];
  const float* mts_b2  = (const float*)d_in[12];
  const float* mts_wv  = (const float*)d_in[13];
  const float* mts_bv  = (const float*)d_in[14];
  const float* ht_w    = (const float*)d_in[15];
  const float* ht_b    = (const float*)d_in[16];
  const float* hts_w   = (const float*)d_in[17];
  const float* hts_b   = (const float*)d_in[18];
  const int*   y       = (const int*)d_in[19];
  const int*   idx     = (const int*)d_in[20];
  float* out = (float*)d_out;
  float* outmem = out + 262144;
  char* ws = (char*)d_ws;

  u16* w2a = (u16*)(ws + 0);
  u16* w2b = (u16*)(ws + 65536);
  u16* wc1 = (u16*)(ws + 131072);
  u16* wc2 = (u16*)(ws + 196608);
  float* c1   = (float*)(ws + 262144);
  float* c2   = (float*)(ws + 294912);
  float* bc1  = (float*)(ws + 327680);
  float* bc2  = (float*)(ws + 328192);
  float* wss  = (float*)(ws + 393216);   // 64*4096 f32 = 1MB

  const size_t PLANES_OFF = 2097152;
  const size_t PLANES_BYTES = (size_t)12800000 * 2 * 2;   // 51.2MB
  const bool bigws = ws_size >= PLANES_OFF + PLANES_BYTES;
  u16 *mh, *ml;
  if (bigws){ mh = (u16*)(ws + PLANES_OFF); }
  else      { mh = (u16*)outmem; }            // park planes in new_memory region
  ml = mh + 12800000;

  // 1. split bank to hi/lo planes (+ fused copy when planes don't alias outmem)
  split_copy_kernel<<<2048, 256, 0, stream>>>((const float4*)mem, (float4*)outmem,
                                              (u16x4*)mh, (u16x4*)ml, 3200000, bigws ? 1 : 0);
  // 2. weights/c/bc prep
  prep_kernel<<<512, 128, 0, stream>>>(v1, v2,
      mt_w1, mt_b1, mt_w2, mt_b2, mt_wv, mt_bv,
      mts_w1, mts_b1, mts_w2, mts_b2, mts_wv, mts_bv,
      ht_w, ht_b, hts_w, hts_b,
      w2a, w2b, wc1, wc2, c1, c2, bc1, bc2);
  // 3. main fused compute -> wss (1024 blocks x 512 thr = 1 block/CU, 4 tiles each)
  main_kernel<<<1024, 512, 0, stream>>>(mh, ml, idx,
      w2a, w2b, wc1, wc2, c1, c2, bc1, bc2, wss);
  // 4. new_memory
  if (!bigws)
    copy_kernel<<<2048, 256, 0, stream>>>((const float4*)mem, (float4*)outmem, 3200000);
  update_kernel<<<64, 128, 0, stream>>>(mem, v2, y, outmem);
  // 5. scores transpose into out
  transpose_kernel<<<64, 256, 0, stream>>>(wss, out);
}